// Round 1
// baseline (755.202 us; speedup 1.0000x reference)
//
#include <hip/hip_runtime.h>
#include <stdint.h>

// ---------------------------------------------------------------------------
// BiGRU + LayerNorm for MI355X (gfx950)
// K0: convert/scale weights to bf16 (log2e folded in; n-gate gets 2*log2e)
// K1: xp = x @ W_ih^T + b_ih  (bf16 MFMA 128x128 tile, fp32 out, scaled)
// K2: serial GRU scan, 8 WGs (4 batch-groups x 2 dirs), 512 thr,
//     C[384 gates][16 batch] = Whh * H^T per step; h resident in fp32 regs
// K3: LayerNorm (unbiased std, clamp 1e-6), in place on d_out
// ---------------------------------------------------------------------------

#define LOG2E 1.4426950408889634f
#define TT 512
#define D_IN 968
#define KP 992
#define NOUT 768
#define HID 128

typedef __attribute__((ext_vector_type(8))) short short8;
typedef __attribute__((ext_vector_type(4))) float f32x4;
typedef __attribute__((ext_vector_type(4))) unsigned int u32x4;
typedef __attribute__((ext_vector_type(2))) unsigned int u32x2;

__device__ __forceinline__ unsigned short f2bf(float f) {
  unsigned u = __builtin_bit_cast(unsigned, f);
  u += 0x7FFFu + ((u >> 16) & 1u);   // RTNE
  return (unsigned short)(u >> 16);
}
__device__ __forceinline__ unsigned pack2bf(float a, float b) {
  return (unsigned)f2bf(a) | ((unsigned)f2bf(b) << 16);
}
__device__ __forceinline__ float exp2_(float x) { return __builtin_amdgcn_exp2f(x); }
__device__ __forceinline__ float rcp_(float x)  { return __builtin_amdgcn_rcpf(x); }

__device__ __forceinline__ void async_load16(const void* g, void* l) {
  __builtin_amdgcn_global_load_lds(
      (const __attribute__((address_space(1))) unsigned int*)g,
      (__attribute__((address_space(3))) unsigned int*)l, 16, 0, 0);
}

// ws layout
#define WIH_BYTES (NOUT * KP * 2)
#define WHH_BYTES (NOUT * HID * 2)
#define BIAS_BYTES (NOUT * 4)
#define XP_OFF (WIH_BYTES + WHH_BYTES + BIAS_BYTES)

// ---------------------------------------------------------------- K0 convert
__global__ __launch_bounds__(256) void k0_convert(
    const float* __restrict__ wihf, const float* __restrict__ whhf,
    const float* __restrict__ bihf, const float* __restrict__ wihb,
    const float* __restrict__ whhb, const float* __restrict__ bihb,
    unsigned short* __restrict__ wih16, unsigned short* __restrict__ whh16,
    float* __restrict__ bias_s) {
  int blk = blockIdx.x, tid = threadIdx.x;
  if (blk < NOUT) {
    int n = blk;
    float sc = ((n % 384) < 256) ? LOG2E : 2.0f * LOG2E;
    const float* src = (n < 384) ? (wihf + (long)n * D_IN) : (wihb + (long)(n - 384) * D_IN);
    for (int c = 0; c < 4; c++) {
      int k = c * 256 + tid;
      if (k < KP) {
        float v = (k < D_IN) ? src[k] * sc : 0.0f;  // zero-pad K to 992
        wih16[(long)n * KP + k] = f2bf(v);
      }
    }
  } else if (blk < NOUT + 96) {
    int e0 = ((blk - NOUT) * 256 + tid) * 4;
    for (int i = 0; i < 4; i++) {
      int e = e0 + i;
      int m = e >> 7, k = e & 127;
      float sc = ((m % 384) < 256) ? LOG2E : 2.0f * LOG2E;
      float v = (m < 384) ? whhf[m * HID + k] : whhb[(m - 384) * HID + k];
      whh16[e] = f2bf(v * sc);
    }
  } else {
    for (int c = 0; c < 3; c++) {
      int n = c * 256 + tid;
      if (n < NOUT) {
        float sc = ((n % 384) < 256) ? LOG2E : 2.0f * LOG2E;
        bias_s[n] = ((n < 384) ? bihf[n] : bihb[n - 384]) * sc;
      }
    }
  }
}

// ---------------------------------------------------------------- K1 GEMM
#define AS_STRIDE 40  // padded (rows 80B) to break ds_write/read bank conflicts

__global__ __launch_bounds__(256, 2) void k1_gemm(
    const float* __restrict__ X, const unsigned short* __restrict__ W,
    const float* __restrict__ bias_s, float* __restrict__ XP) {
  __shared__ unsigned short As[128 * AS_STRIDE];
  __shared__ unsigned short Bs[128 * 32];

  const int tid = threadIdx.x;
  const int lane = tid & 63, w = tid >> 6;
  const int q = lane >> 4, l15 = lane & 15;
  const int wr = w >> 1, wc = w & 1;
  const int nt = blockIdx.x;            // 0..5  (fast: consecutive WGs share A-tile)
  const int mt = blockIdx.y;            // 0..255
  const long R0 = (long)mt * 128;
  const int C0 = nt * 128;
  const int ar = tid >> 1, ahf = tid & 1;

  f32x4 acc[4][4];
#pragma unroll
  for (int i = 0; i < 4; i++)
#pragma unroll
    for (int j = 0; j < 4; j++) acc[i][j] = {0.f, 0.f, 0.f, 0.f};

  const float* arow = X + (R0 + ar) * D_IN;

  for (int it = 0; it < 31; it++) {
    int k0 = it * 32;
    // A stage: fp32 -> bf16 (tail cols clamped; B side is zero-padded so
    // garbage A values at k>=968 multiply zeros)
    unsigned pk[8];
#pragma unroll
    for (int c = 0; c < 4; c++) {
      int kc = k0 + ahf * 16 + c * 4;
      kc = (kc <= 964) ? kc : 964;
      f32x4 v = *(const f32x4*)(arow + kc);
      pk[c * 2 + 0] = pack2bf(v.x, v.y);
      pk[c * 2 + 1] = pack2bf(v.z, v.w);
    }
    unsigned short* adst = &As[ar * AS_STRIDE + ahf * 16];
    u32x4 w0 = {pk[0], pk[1], pk[2], pk[3]};
    u32x4 w1 = {pk[4], pk[5], pk[6], pk[7]};
    *(u32x4*)adst = w0;
    *(u32x4*)(adst + 8) = w1;
    // B stage: async global->LDS, 16B/lane
#pragma unroll
    for (int c = 0; c < 2; c++) {
      int idx = c * 256 + w * 64 + lane;
      int brow = idx >> 2, koff = (idx & 3) * 8;
      const unsigned short* gsrc = W + (long)(C0 + brow) * KP + k0 + koff;
      async_load16(gsrc, ((char*)Bs) + (c * 256 + w * 64) * 16);
    }
    __syncthreads();
    short8 af[4], bf[4];
#pragma unroll
    for (int i = 0; i < 4; i++) {
      int m = wr * 64 + i * 16 + l15;
      af[i] = *(const short8*)&As[m * AS_STRIDE + q * 8];
    }
#pragma unroll
    for (int j = 0; j < 4; j++) {
      int n = wc * 64 + j * 16 + l15;
      bf[j] = *(const short8*)&Bs[n * 32 + q * 8];
    }
#pragma unroll
    for (int i = 0; i < 4; i++)
#pragma unroll
      for (int j = 0; j < 4; j++)
        acc[i][j] = __builtin_amdgcn_mfma_f32_16x16x32_bf16(af[i], bf[j], acc[i][j], 0, 0, 0);
    __syncthreads();
  }
  float bv[4];
#pragma unroll
  for (int j = 0; j < 4; j++) bv[j] = bias_s[C0 + wc * 64 + j * 16 + l15];
#pragma unroll
  for (int i = 0; i < 4; i++)
#pragma unroll
    for (int j = 0; j < 4; j++) {
      int col = C0 + wc * 64 + j * 16 + l15;
      long Rb = R0 + wr * 64 + i * 16 + q * 4;
#pragma unroll
      for (int r = 0; r < 4; r++)
        XP[(Rb + r) * NOUT + col] = acc[i][j][r] + bv[j];
    }
}

// ---------------------------------------------------------------- K2 GRU scan
#define GI_STRIDE 52  // floats; 208B rows, 16B aligned, low-conflict

__global__ __launch_bounds__(512) void k2_gru(
    const unsigned short* __restrict__ WHH, const float* __restrict__ XP,
    const float* __restrict__ bhh_f, const float* __restrict__ bhh_b,
    float* __restrict__ OUT) {
  // H buffers: [2][16 rows][128] bf16, chunk-of-8 XOR-swizzled by (row&7)
  __shared__ unsigned short Hl[2][16 * 128];
  __shared__ float GIl[8][16 * GI_STRIDE];  // wave-private gi staging

  const int tid = threadIdx.x;
  const int lane = tid & 63, w = tid >> 6;  // 8 waves; wave w owns j in [16w,16w+16)
  const int q = lane >> 4, b = lane & 15;
  const int dir = blockIdx.x & 1, bg = blockIdx.x >> 1;
  const int j0 = w * 16 + q * 4;

  for (int i = tid; i < 2 * 16 * 128; i += 512) ((unsigned short*)Hl)[i] = 0;

  // resident Whh A-fragments: rows = dir*384 + g*128 + 16w + (lane&15)
  short8 afr[3][4];
#pragma unroll
  for (int g = 0; g < 3; g++)
#pragma unroll
    for (int kt = 0; kt < 4; kt++) {
      int row = dir * 384 + g * 128 + w * 16 + b;
      afr[g][kt] = *(const short8*)(WHH + (long)row * HID + kt * 32 + q * 8);
    }
  const float* bhh = dir ? bhh_b : bhh_f;
  f32x4 bh[3];
#pragma unroll
  for (int g = 0; g < 3; g++) {
    f32x4 t = *(const f32x4*)(bhh + g * 128 + j0);
    float sc = (g < 2) ? LOG2E : 2.0f * LOG2E;
    bh[g] = t * sc;
  }

  // gi loader mapping: lane -> (batch lb, 4-col chunk lc); coalesced dwordx4
  const int lb = lane >> 2, lc = lane & 3;
  const long gi_base = (long)(bg * 16 + lb) * TT * NOUT + dir * 384 + w * 16 + lc * 4;
  float* giw = &GIl[w][lb * GI_STRIDE + lc * 4];
  const float* gir = &GIl[w][b * GI_STRIDE];
  const long out_base = (long)(bg * 16 + b) * TT * 256 + dir * 128 + j0;

  // prologue: gi(t=0)
  {
    int td0 = dir ? (TT - 1) : 0;
    const float* gb = XP + gi_base + (long)td0 * NOUT;
    f32x4 g0 = *(const f32x4*)(gb);
    f32x4 g1 = *(const f32x4*)(gb + 128);
    f32x4 g2 = *(const f32x4*)(gb + 256);
    *(f32x4*)(giw + 0) = g0;
    *(f32x4*)(giw + 16) = g1;
    *(f32x4*)(giw + 32) = g2;
  }
  f32x4 h = {0.f, 0.f, 0.f, 0.f};  // fp32-resident recurrent state (accuracy)
  __syncthreads();

  for (int t = 0; t < TT; t++) {
    const int cur = t & 1, nxt = cur ^ 1;
    const int td = dir ? (TT - 1 - t) : t;
    const int tn = (t + 1 < TT) ? t + 1 : t;
    const int tdn = dir ? (TT - 1 - tn) : tn;

    // B-fragments: H rows = batch (lane&15), swizzled chunks
    short8 bfr[4];
#pragma unroll
    for (int kt = 0; kt < 4; kt++) {
      int ch = ((kt * 4 + q) ^ (b & 7)) * 8;
      bfr[kt] = *(const short8*)&Hl[cur][b * 128 + ch];
    }
    f32x4 accR = {0.f, 0.f, 0.f, 0.f};
    f32x4 accZ = {0.f, 0.f, 0.f, 0.f};
    f32x4 accN = {0.f, 0.f, 0.f, 0.f};
#pragma unroll
    for (int kt = 0; kt < 4; kt++) {
      accR = __builtin_amdgcn_mfma_f32_16x16x32_bf16(afr[0][kt], bfr[kt], accR, 0, 0, 0);
      accZ = __builtin_amdgcn_mfma_f32_16x16x32_bf16(afr[1][kt], bfr[kt], accZ, 0, 0, 0);
      accN = __builtin_amdgcn_mfma_f32_16x16x32_bf16(afr[2][kt], bfr[kt], accN, 0, 0, 0);
    }
    // prefetch gi(t+1) to regs (latency hidden behind gate math)
    const float* gb = XP + gi_base + (long)tdn * NOUT;
    f32x4 gp0 = *(const f32x4*)(gb);
    f32x4 gp1 = *(const f32x4*)(gb + 128);
    f32x4 gp2 = *(const f32x4*)(gb + 256);

    // gate math (all preacts pre-scaled by log2e / 2log2e -> raw exp2)
    f32x4 gr = *(const f32x4*)(gir + 0 + q * 4);
    f32x4 gz = *(const f32x4*)(gir + 16 + q * 4);
    f32x4 gn = *(const f32x4*)(gir + 32 + q * 4);
    f32x4 hnew;
#pragma unroll
    for (int i = 0; i < 4; i++) {
      float pr = gr[i] + accR[i] + bh[0][i];
      float pz = gz[i] + accZ[i] + bh[1][i];
      float r = rcp_(1.0f + exp2_(-pr));
      float z = rcp_(1.0f + exp2_(-pz));
      float pn = gn[i] + r * (accN[i] + bh[2][i]);
      float n = 1.0f - 2.0f * rcp_(exp2_(pn) + 1.0f);
      hnew[i] = n + z * (h[i] - n);
    }
    h = hnew;
    // h' -> LDS (bf16, swizzled) for next step's MFMA
    {
      int ch = ((j0 >> 3) ^ (b & 7)) * 8 + (j0 & 7);
      u32x2 hv = {pack2bf(hnew[0], hnew[1]), pack2bf(hnew[2], hnew[3])};
      *(u32x2*)&Hl[nxt][b * 128 + ch] = hv;
    }
    // h' -> global (pre-LN output)
    *(f32x4*)(OUT + out_base + (long)td * 256) = hnew;
    // stash prefetched gi (after this step's gi reads; wave-private, no barrier)
    *(f32x4*)(giw + 0) = gp0;
    *(f32x4*)(giw + 16) = gp1;
    *(f32x4*)(giw + 32) = gp2;
    __syncthreads();
  }
}

// ---------------------------------------------------------------- K3 LayerNorm
__global__ __launch_bounds__(256) void k3_ln(float* __restrict__ OUT,
                                             const float* __restrict__ lnw,
                                             const float* __restrict__ lnb) {
  const int tid = threadIdx.x, lane = tid & 63, w = tid >> 6;
  const long row = (long)blockIdx.x * 4 + w;
  float* p = OUT + row * 256 + lane * 4;
  f32x4 x = *(const f32x4*)p;
  float s = x[0] + x[1] + x[2] + x[3];
  float s2 = x[0] * x[0] + x[1] * x[1] + x[2] * x[2] + x[3] * x[3];
#pragma unroll
  for (int m = 1; m < 64; m <<= 1) {
    s += __shfl_xor(s, m, 64);
    s2 += __shfl_xor(s2, m, 64);
  }
  float mu = s * (1.0f / 256.0f);
  float var = (s2 - s * mu) * (1.0f / 255.0f);  // ddof=1
  var = fmaxf(var, 0.0f);
  float sig = fmaxf(sqrtf(var), 1e-6f);
  float inv = 1.0f / sig;
  f32x4 wv = *(const f32x4*)(lnw + lane * 4);
  f32x4 bv = *(const f32x4*)(lnb + lane * 4);
  f32x4 y;
#pragma unroll
  for (int i = 0; i < 4; i++) y[i] = (x[i] - mu) * inv * wv[i] + bv[i];
  *(f32x4*)p = y;
}

// ---------------------------------------------------------------- launch
extern "C" void kernel_launch(void* const* d_in, const int* in_sizes, int n_in,
                              void* d_out, int out_size, void* d_ws, size_t ws_size,
                              hipStream_t stream) {
  const float* x = (const float*)d_in[0];
  const float* wihf = (const float*)d_in[1];
  const float* whhf = (const float*)d_in[2];
  const float* bihf = (const float*)d_in[3];
  const float* bhhf = (const float*)d_in[4];
  const float* wihb = (const float*)d_in[5];
  const float* whhb = (const float*)d_in[6];
  const float* bihb = (const float*)d_in[7];
  const float* bhhb = (const float*)d_in[8];
  const float* lnw = (const float*)d_in[9];
  const float* lnb = (const float*)d_in[10];

  char* ws = (char*)d_ws;
  unsigned short* wih16 = (unsigned short*)ws;
  unsigned short* whh16 = (unsigned short*)(ws + WIH_BYTES);
  float* bias_s = (float*)(ws + WIH_BYTES + WHH_BYTES);
  float* xp = (float*)(ws + XP_OFF);  // ~96MB fp32 [32768][768]
  float* out = (float*)d_out;

  hipLaunchKernelGGL(k0_convert, dim3(768 + 96 + 1), dim3(256), 0, stream,
                     wihf, whhf, bihf, wihb, whhb, bihb, wih16, whh16, bias_s);
  hipLaunchKernelGGL(k1_gemm, dim3(6, 256), dim3(256), 0, stream, x, wih16, bias_s, xp);
  hipLaunchKernelGGL(k2_gru, dim3(8), dim3(512), 0, stream, whh16, xp, bhhf, bhhb, out);
  hipLaunchKernelGGL(k3_ln, dim3(8192), dim3(256), 0, stream, out, lnw, lnb);
}

// Round 2
// 678.239 us; speedup vs baseline: 1.1135x; 1.1135x over previous
//
#include <hip/hip_runtime.h>
#include <stdint.h>

// ---------------------------------------------------------------------------
// BiGRU + LayerNorm for MI355X (gfx950)
// kx: X fp32 -> bf16 (padded K 968->992), once
// k0: convert/scale weights to bf16 (log2e folded in; n-gate gets 2*log2e)
// k1: xp = x @ W_ih^T + b_ih  (m97-style: global_load_lds x16B both operands)
// k2: serial GRU scan, 8 WGs, raw s_barrier (NO vmcnt drain), dist-2 prefetch
// k3: LayerNorm (unbiased std, clamp 1e-6), in place on d_out
// ---------------------------------------------------------------------------

#define LOG2E 1.4426950408889634f
#define TT 512
#define D_IN 968
#define KP 992
#define NOUT 768
#define HID 128

typedef __attribute__((ext_vector_type(8))) short short8;
typedef __attribute__((ext_vector_type(4))) float f32x4;
typedef __attribute__((ext_vector_type(4))) unsigned int u32x4;
typedef __attribute__((ext_vector_type(2))) unsigned int u32x2;

__device__ __forceinline__ unsigned short f2bf(float f) {
  unsigned u = __builtin_bit_cast(unsigned, f);
  u += 0x7FFFu + ((u >> 16) & 1u);   // RTNE
  return (unsigned short)(u >> 16);
}
__device__ __forceinline__ unsigned pack2bf(float a, float b) {
  return (unsigned)f2bf(a) | ((unsigned)f2bf(b) << 16);
}
__device__ __forceinline__ float exp2_(float x) { return __builtin_amdgcn_exp2f(x); }
__device__ __forceinline__ float rcp_(float x)  { return __builtin_amdgcn_rcpf(x); }

__device__ __forceinline__ void async_load16(const void* g, void* l) {
  __builtin_amdgcn_global_load_lds(
      (const __attribute__((address_space(1))) unsigned int*)g,
      (__attribute__((address_space(3))) unsigned int*)l, 16, 0, 0);
}

// workgroup barrier that does NOT drain vmcnt (only LDS visibility).
// Safe here: cross-wave data exchange is exclusively through LDS (Hl),
// which is double-buffered across the barrier.
__device__ __forceinline__ void wg_barrier_lds() {
  asm volatile("s_waitcnt lgkmcnt(0)\n\ts_barrier" ::: "memory");
}

// ws layout
#define WIH_BYTES (NOUT * KP * 2)            // 1,523,712
#define WHH_BYTES (NOUT * HID * 2)           // 196,608
#define BIAS_BYTES 3072
#define BASE_OFF (WIH_BYTES + WHH_BYTES + BIAS_BYTES)  // 1,723,392 (256-aligned)
#define XBF_BYTES ((size_t)32768 * KP * 2)   // 65,011,712
#define XP_BYTES ((size_t)32768 * NOUT * 4)  // 100,663,296

// ---------------------------------------------------------------- kx: X->bf16
__global__ __launch_bounds__(256) void kx_convert(const float* __restrict__ X,
                                                  unsigned short* __restrict__ Xb) {
  const long row = blockIdx.x;
  const int t = threadIdx.x;  // chunk of 4 cols; 968/4 = 242 full chunks
  if (t < 242) {
    f32x4 v = *(const f32x4*)(X + row * D_IN + t * 4);
    u32x2 p = {pack2bf(v.x, v.y), pack2bf(v.z, v.w)};
    *(u32x2*)(Xb + row * KP + t * 4) = p;
  } else if (t < 248) {
    *(u32x2*)(Xb + row * KP + t * 4) = (u32x2){0, 0};  // zero-pad 968..991
  }
}

// ---------------------------------------------------------------- K0 convert
__global__ __launch_bounds__(256) void k0_convert(
    const float* __restrict__ wihf, const float* __restrict__ whhf,
    const float* __restrict__ bihf, const float* __restrict__ wihb,
    const float* __restrict__ whhb, const float* __restrict__ bihb,
    unsigned short* __restrict__ wih16, unsigned short* __restrict__ whh16,
    float* __restrict__ bias_s) {
  int blk = blockIdx.x, tid = threadIdx.x;
  if (blk < NOUT) {
    int n = blk;
    float sc = ((n % 384) < 256) ? LOG2E : 2.0f * LOG2E;
    const float* src = (n < 384) ? (wihf + (long)n * D_IN) : (wihb + (long)(n - 384) * D_IN);
    for (int c = 0; c < 4; c++) {
      int k = c * 256 + tid;
      if (k < KP) {
        float v = (k < D_IN) ? src[k] * sc : 0.0f;
        wih16[(long)n * KP + k] = f2bf(v);
      }
    }
  } else if (blk < NOUT + 96) {
    int e0 = ((blk - NOUT) * 256 + tid) * 4;
    for (int i = 0; i < 4; i++) {
      int e = e0 + i;
      int m = e >> 7, k = e & 127;
      float sc = ((m % 384) < 256) ? LOG2E : 2.0f * LOG2E;
      float v = (m < 384) ? whhf[m * HID + k] : whhb[(m - 384) * HID + k];
      whh16[e] = f2bf(v * sc);
    }
  } else {
    for (int c = 0; c < 3; c++) {
      int n = c * 256 + tid;
      if (n < NOUT) {
        float sc = ((n % 384) < 256) ? LOG2E : 2.0f * LOG2E;
        bias_s[n] = ((n < 384) ? bihf[n] : bihb[n - 384]) * sc;
      }
    }
  }
}

// ---------------------------------------------------------------- K1 fast GEMM
// m97 structure: both A (Xb, pre-converted bf16) and B staged via
// global_load_lds width 16. LDS rows stride 32 shorts (required by the
// wave-uniform-base + lane*16 rule).
__global__ __launch_bounds__(256, 2) void k1_gemm_fast(
    const unsigned short* __restrict__ Xb, const unsigned short* __restrict__ W,
    const float* __restrict__ bias_s, float* __restrict__ XP) {
  __shared__ unsigned short As[128 * 32];
  __shared__ unsigned short Bs[128 * 32];

  const int tid = threadIdx.x;
  const int lane = tid & 63, w = tid >> 6;
  const int q = lane >> 4, l15 = lane & 15;
  const int wr = w >> 1, wc = w & 1;
  const int nt = blockIdx.x;   // 0..5 fast -> consecutive WGs share A-tile (L2)
  const int mt = blockIdx.y;   // 0..255
  const long R0 = (long)mt * 128;
  const int C0 = nt * 128;

  f32x4 acc[4][4];
#pragma unroll
  for (int i = 0; i < 4; i++)
#pragma unroll
    for (int j = 0; j < 4; j++) acc[i][j] = {0.f, 0.f, 0.f, 0.f};

  for (int it = 0; it < 31; it++) {
    const int k0 = it * 32;
#pragma unroll
    for (int c = 0; c < 2; c++) {
      int idx = c * 256 + w * 64 + lane;
      int row = idx >> 2, koff = (idx & 3) * 8;
      async_load16(Xb + (R0 + row) * KP + k0 + koff,
                   ((char*)As) + (c * 256 + w * 64) * 16);
      async_load16(W + (long)(C0 + row) * KP + k0 + koff,
                   ((char*)Bs) + (c * 256 + w * 64) * 16);
    }
    __syncthreads();  // drains vmcnt -> global_load_lds complete (m97 pattern)
    short8 af[4], bf[4];
#pragma unroll
    for (int i = 0; i < 4; i++)
      af[i] = *(const short8*)&As[(wr * 64 + i * 16 + l15) * 32 + q * 8];
#pragma unroll
    for (int j = 0; j < 4; j++)
      bf[j] = *(const short8*)&Bs[(wc * 64 + j * 16 + l15) * 32 + q * 8];
#pragma unroll
    for (int i = 0; i < 4; i++)
#pragma unroll
      for (int j = 0; j < 4; j++)
        acc[i][j] = __builtin_amdgcn_mfma_f32_16x16x32_bf16(af[i], bf[j], acc[i][j], 0, 0, 0);
    __syncthreads();
  }
  float bv[4];
#pragma unroll
  for (int j = 0; j < 4; j++) bv[j] = bias_s[C0 + wc * 64 + j * 16 + l15];
#pragma unroll
  for (int i = 0; i < 4; i++)
#pragma unroll
    for (int j = 0; j < 4; j++) {
      int col = C0 + wc * 64 + j * 16 + l15;
      long Rb = R0 + wr * 64 + i * 16 + q * 4;
#pragma unroll
      for (int r = 0; r < 4; r++)
        XP[(Rb + r) * NOUT + col] = acc[i][j][r] + bv[j];
    }
}

// ---------------------------------------------------------------- K1 slow GEMM
// (fallback if ws too small for Xbf: inline fp32->bf16 A staging, round-1 path)
#define AS_STRIDE 40
__global__ __launch_bounds__(256, 2) void k1_gemm_slow(
    const float* __restrict__ X, const unsigned short* __restrict__ W,
    const float* __restrict__ bias_s, float* __restrict__ XP) {
  __shared__ unsigned short As[128 * AS_STRIDE];
  __shared__ unsigned short Bs[128 * 32];
  const int tid = threadIdx.x;
  const int lane = tid & 63, w = tid >> 6;
  const int q = lane >> 4, l15 = lane & 15;
  const int wr = w >> 1, wc = w & 1;
  const int nt = blockIdx.x, mt = blockIdx.y;
  const long R0 = (long)mt * 128;
  const int C0 = nt * 128;
  const int ar = tid >> 1, ahf = tid & 1;
  f32x4 acc[4][4];
#pragma unroll
  for (int i = 0; i < 4; i++)
#pragma unroll
    for (int j = 0; j < 4; j++) acc[i][j] = {0.f, 0.f, 0.f, 0.f};
  const float* arow = X + (R0 + ar) * D_IN;
  for (int it = 0; it < 31; it++) {
    int k0 = it * 32;
    unsigned pk[8];
#pragma unroll
    for (int c = 0; c < 4; c++) {
      int kc = k0 + ahf * 16 + c * 4;
      kc = (kc <= 964) ? kc : 964;
      f32x4 v = *(const f32x4*)(arow + kc);
      pk[c * 2 + 0] = pack2bf(v.x, v.y);
      pk[c * 2 + 1] = pack2bf(v.z, v.w);
    }
    unsigned short* adst = &As[ar * AS_STRIDE + ahf * 16];
    *(u32x4*)adst = (u32x4){pk[0], pk[1], pk[2], pk[3]};
    *(u32x4*)(adst + 8) = (u32x4){pk[4], pk[5], pk[6], pk[7]};
#pragma unroll
    for (int c = 0; c < 2; c++) {
      int idx = c * 256 + w * 64 + lane;
      int brow = idx >> 2, koff = (idx & 3) * 8;
      async_load16(W + (long)(C0 + brow) * KP + k0 + koff,
                   ((char*)Bs) + (c * 256 + w * 64) * 16);
    }
    __syncthreads();
    short8 af[4], bf[4];
#pragma unroll
    for (int i = 0; i < 4; i++)
      af[i] = *(const short8*)&As[(wr * 64 + i * 16 + l15) * AS_STRIDE + q * 8];
#pragma unroll
    for (int j = 0; j < 4; j++)
      bf[j] = *(const short8*)&Bs[(wc * 64 + j * 16 + l15) * 32 + q * 8];
#pragma unroll
    for (int i = 0; i < 4; i++)
#pragma unroll
      for (int j = 0; j < 4; j++)
        acc[i][j] = __builtin_amdgcn_mfma_f32_16x16x32_bf16(af[i], bf[j], acc[i][j], 0, 0, 0);
    __syncthreads();
  }
  float bv[4];
#pragma unroll
  for (int j = 0; j < 4; j++) bv[j] = bias_s[C0 + wc * 64 + j * 16 + l15];
#pragma unroll
  for (int i = 0; i < 4; i++)
#pragma unroll
    for (int j = 0; j < 4; j++) {
      int col = C0 + wc * 64 + j * 16 + l15;
      long Rb = R0 + wr * 64 + i * 16 + q * 4;
#pragma unroll
      for (int r = 0; r < 4; r++)
        XP[(Rb + r) * NOUT + col] = acc[i][j][r] + bv[j];
    }
}

// ---------------------------------------------------------------- K2 GRU scan
#define GI_STRIDE 52  // floats; 16B-aligned rows, balanced bank pattern

__global__ __launch_bounds__(512) void k2_gru(
    const unsigned short* __restrict__ WHH, const float* __restrict__ XP,
    const float* __restrict__ bhh_f, const float* __restrict__ bhh_b,
    float* __restrict__ OUT) {
  __shared__ unsigned short Hl[2][16 * 128];      // double-buffered H (bf16, swizzled)
  __shared__ float GIl[2][8][16 * GI_STRIDE];     // double-buffered wave-private gi

  const int tid = threadIdx.x;
  const int lane = tid & 63, w = tid >> 6;  // wave w owns cols [16w,16w+16)
  const int q = lane >> 4, b = lane & 15;
  const int dir = blockIdx.x & 1, bg = blockIdx.x >> 1;
  const int j0 = w * 16 + q * 4;

  for (int i = tid; i < 2 * 16 * 128; i += 512) ((unsigned short*)Hl)[i] = 0;

  // resident Whh A-fragments
  short8 afr[3][4];
#pragma unroll
  for (int g = 0; g < 3; g++)
#pragma unroll
    for (int kt = 0; kt < 4; kt++) {
      int row = dir * 384 + g * 128 + w * 16 + b;
      afr[g][kt] = *(const short8*)(WHH + (long)row * HID + kt * 32 + q * 8);
    }
  const float* bhh = dir ? bhh_b : bhh_f;
  f32x4 bh[3];
#pragma unroll
  for (int g = 0; g < 3; g++) {
    f32x4 t = *(const f32x4*)(bhh + g * 128 + j0);
    bh[g] = t * ((g < 2) ? LOG2E : 2.0f * LOG2E);
  }

  // gi loader mapping: lane -> (batch lb, 4-col chunk lc); coalesced dwordx4
  const int lb = lane >> 2, lc = lane & 3;
  const long gi_base = (long)(bg * 16 + lb) * TT * NOUT + dir * 384 + w * 16 + lc * 4;
  const long out_base = (long)(bg * 16 + b) * TT * 256 + dir * 128 + j0;

  // prologue: gi(0) -> GIl[0]; gi(1) held in regs across the loop entry
  f32x4 gp0, gp1, gp2;
  {
    const int td0 = dir ? (TT - 1) : 0;
    const float* gb = XP + gi_base + (long)td0 * NOUT;
    f32x4 a0 = *(const f32x4*)(gb);
    f32x4 a1 = *(const f32x4*)(gb + 128);
    f32x4 a2 = *(const f32x4*)(gb + 256);
    float* giw0 = &GIl[0][w][lb * GI_STRIDE + lc * 4];
    *(f32x4*)(giw0 + 0) = a0;
    *(f32x4*)(giw0 + 16) = a1;
    *(f32x4*)(giw0 + 32) = a2;
    const int td1 = dir ? (TT - 2) : 1;
    const float* gb1 = XP + gi_base + (long)td1 * NOUT;
    gp0 = *(const f32x4*)(gb1);
    gp1 = *(const f32x4*)(gb1 + 128);
    gp2 = *(const f32x4*)(gb1 + 256);
  }
  f32x4 h = {0.f, 0.f, 0.f, 0.f};
  __syncthreads();  // one full barrier pre-loop is fine

  for (int t = 0; t < TT; t++) {
    const int cur = t & 1, nxt = cur ^ 1;
    const int td = dir ? (TT - 1 - t) : t;

    // 1) H B-fragments from Hl[cur] (issue first; MFMA waits on these)
    short8 bfr[4];
#pragma unroll
    for (int kt = 0; kt < 4; kt++) {
      int ch = ((kt * 4 + q) ^ (b & 7)) * 8;
      bfr[kt] = *(const short8*)&Hl[cur][b * 128 + ch];
    }
    // 2) stash gi(t+1) (loaded a full step ago) into GIl[nxt]
    {
      float* giw = &GIl[nxt][w][lb * GI_STRIDE + lc * 4];
      *(f32x4*)(giw + 0) = gp0;
      *(f32x4*)(giw + 16) = gp1;
      *(f32x4*)(giw + 32) = gp2;
    }
    // 3) issue load gi(t+2) -> regs (consumed at step t+1's stash)
    {
      int tn2 = (t + 2 < TT) ? t + 2 : TT - 1;
      int tdn2 = dir ? (TT - 1 - tn2) : tn2;
      const float* gb = XP + gi_base + (long)tdn2 * NOUT;
      gp0 = *(const f32x4*)(gb);
      gp1 = *(const f32x4*)(gb + 128);
      gp2 = *(const f32x4*)(gb + 256);
    }
    // 4) MFMA: 3 independent chains of 4
    f32x4 accR = {0.f, 0.f, 0.f, 0.f};
    f32x4 accZ = {0.f, 0.f, 0.f, 0.f};
    f32x4 accN = {0.f, 0.f, 0.f, 0.f};
#pragma unroll
    for (int kt = 0; kt < 4; kt++) {
      accR = __builtin_amdgcn_mfma_f32_16x16x32_bf16(afr[0][kt], bfr[kt], accR, 0, 0, 0);
      accZ = __builtin_amdgcn_mfma_f32_16x16x32_bf16(afr[1][kt], bfr[kt], accZ, 0, 0, 0);
      accN = __builtin_amdgcn_mfma_f32_16x16x32_bf16(afr[2][kt], bfr[kt], accN, 0, 0, 0);
    }
    // 5) gi(t) from GIl[cur] (stashed at step t-1; wave-private, no barrier)
    const float* gir = &GIl[cur][w][b * GI_STRIDE];
    f32x4 gr = *(const f32x4*)(gir + 0 + q * 4);
    f32x4 gz = *(const f32x4*)(gir + 16 + q * 4);
    f32x4 gn = *(const f32x4*)(gir + 32 + q * 4);
    // 6) gate math (preacts pre-scaled by log2e / 2log2e)
    f32x4 hnew;
#pragma unroll
    for (int i = 0; i < 4; i++) {
      float pr = gr[i] + accR[i] + bh[0][i];
      float pz = gz[i] + accZ[i] + bh[1][i];
      float r = rcp_(1.0f + exp2_(-pr));
      float z = rcp_(1.0f + exp2_(-pz));
      float pn = gn[i] + r * (accN[i] + bh[2][i]);
      float n = 1.0f - 2.0f * rcp_(exp2_(pn) + 1.0f);
      hnew[i] = n + z * (h[i] - n);
    }
    h = hnew;
    // 7) h' -> Hl[nxt] (bf16, swizzled) and global OUT (fp32)
    {
      int ch = ((j0 >> 3) ^ (b & 7)) * 8 + (j0 & 7);
      u32x2 hv = {pack2bf(hnew[0], hnew[1]), pack2bf(hnew[2], hnew[3])};
      *(u32x2*)&Hl[nxt][b * 128 + ch] = hv;
    }
    *(f32x4*)(OUT + out_base + (long)td * 256) = hnew;
    // 8) barrier WITHOUT vmcnt drain: gi(t+2) load + OUT store stay in flight
    wg_barrier_lds();
  }
}

// ---------------------------------------------------------------- K3 LayerNorm
__global__ __launch_bounds__(256) void k3_ln(float* __restrict__ OUT,
                                             const float* __restrict__ lnw,
                                             const float* __restrict__ lnb) {
  const int tid = threadIdx.x, lane = tid & 63, w = tid >> 6;
  const long row = (long)blockIdx.x * 4 + w;
  float* p = OUT + row * 256 + lane * 4;
  f32x4 x = *(const f32x4*)p;
  float s = x[0] + x[1] + x[2] + x[3];
  float s2 = x[0] * x[0] + x[1] * x[1] + x[2] * x[2] + x[3] * x[3];
#pragma unroll
  for (int m = 1; m < 64; m <<= 1) {
    s += __shfl_xor(s, m, 64);
    s2 += __shfl_xor(s2, m, 64);
  }
  float mu = s * (1.0f / 256.0f);
  float var = (s2 - s * mu) * (1.0f / 255.0f);  // ddof=1
  var = fmaxf(var, 0.0f);
  float sig = fmaxf(sqrtf(var), 1e-6f);
  float inv = 1.0f / sig;
  f32x4 wv = *(const f32x4*)(lnw + lane * 4);
  f32x4 bv = *(const f32x4*)(lnb + lane * 4);
  f32x4 y;
#pragma unroll
  for (int i = 0; i < 4; i++) y[i] = (x[i] - mu) * inv * wv[i] + bv[i];
  *(f32x4*)p = y;
}

// ---------------------------------------------------------------- launch
extern "C" void kernel_launch(void* const* d_in, const int* in_sizes, int n_in,
                              void* d_out, int out_size, void* d_ws, size_t ws_size,
                              hipStream_t stream) {
  const float* x = (const float*)d_in[0];
  const float* wihf = (const float*)d_in[1];
  const float* whhf = (const float*)d_in[2];
  const float* bihf = (const float*)d_in[3];
  const float* bhhf = (const float*)d_in[4];
  const float* wihb = (const float*)d_in[5];
  const float* whhb = (const float*)d_in[6];
  const float* bihb = (const float*)d_in[7];
  const float* bhhb = (const float*)d_in[8];
  const float* lnw = (const float*)d_in[9];
  const float* lnb = (const float*)d_in[10];

  char* ws = (char*)d_ws;
  unsigned short* wih16 = (unsigned short*)ws;
  unsigned short* whh16 = (unsigned short*)(ws + WIH_BYTES);
  float* bias_s = (float*)(ws + WIH_BYTES + WHH_BYTES);
  float* out = (float*)d_out;

  const size_t need_fast = (size_t)BASE_OFF + XBF_BYTES + XP_BYTES;  // ~167.4 MB

  hipLaunchKernelGGL(k0_convert, dim3(768 + 96 + 1), dim3(256), 0, stream,
                     wihf, whhf, bihf, wihb, whhb, bihb, wih16, whh16, bias_s);

  float* xp;
  if (ws_size >= need_fast) {
    unsigned short* xbf = (unsigned short*)(ws + BASE_OFF);
    xp = (float*)(ws + BASE_OFF + XBF_BYTES);
    hipLaunchKernelGGL(kx_convert, dim3(32768), dim3(256), 0, stream, x, xbf);
    hipLaunchKernelGGL(k1_gemm_fast, dim3(6, 256), dim3(256), 0, stream,
                       xbf, wih16, bias_s, xp);
  } else {
    xp = (float*)(ws + BASE_OFF);
    hipLaunchKernelGGL(k1_gemm_slow, dim3(6, 256), dim3(256), 0, stream,
                       x, wih16, bias_s, xp);
  }
  hipLaunchKernelGGL(k2_gru, dim3(8), dim3(512), 0, stream, whh16, xp, bhhf, bhhb, out);
  hipLaunchKernelGGL(k3_ln, dim3(8192), dim3(256), 0, stream, out, lnw, lnb);
}